// Round 2
// baseline (139.605 us; speedup 1.0000x reference)
//
#include <hip/hip_runtime.h>

#define SEQ 4096
#define DIM 64
#define CHUNK 128
#define NC 32
#define EPSV 1e-10f
#define KS_OFF 2097152   // float offset of ksum region (S region = 1024 chunks * 4096 bf16 = 8 MiB)

typedef __attribute__((ext_vector_type(8))) short s16x8;   // 8 bf16 (4 VGPRs)
typedef __attribute__((ext_vector_type(4))) float f32x4;   // MFMA C/D

__device__ __forceinline__ unsigned short f2bf(float f) {
  unsigned int u = __float_as_uint(f);
  u += 0x7FFF + ((u >> 16) & 1);          // RNE (inputs are finite)
  return (unsigned short)(u >> 16);
}
__device__ __forceinline__ float bf2f_lo(unsigned int x) { return __uint_as_float(x << 16); }

// native packed f32->bf16 (RNE), src0 -> low16, src1 -> high16
__device__ __forceinline__ unsigned int cvtpk(float lo, float hi) {
  unsigned int r;
  asm("v_cvt_pk_bf16_f32 %0, %1, %2" : "=v"(r) : "v"(lo), "v"(hi));
  return r;
}
__device__ __forceinline__ s16x8 pack8(float4 a, float4 b) {
  union { unsigned int u[4]; s16x8 v; } r;
  r.u[0] = cvtpk(a.x, a.y); r.u[1] = cvtpk(a.z, a.w);
  r.u[2] = cvtpk(b.x, b.y); r.u[3] = cvtpk(b.z, b.w);
  return r.v;
}

// Coalesced transposed gather: global [128][64] f32 row-major -> LDS T[d][j] bf16, stride 136.
// Lane d reads 64 consecutive dwords per instruction (perfect coalescing).
template<bool SUM, int TPB>
__device__ __forceinline__ float gather_T(const float* __restrict__ gp,
                                          unsigned short* __restrict__ dst, int t) {
  int d = t & 63, grp = t >> 6;
  constexpr int GRPS = TPB / 64;
  constexpr int NI = 16 / GRPS;
  float s = 0.f;
#pragma unroll
  for (int i = 0; i < NI; ++i) {
    int j8 = grp + i * GRPS;
    const float* p = gp + (size_t)(j8 * 8) * DIM + d;
    float x[8];
#pragma unroll
    for (int u2 = 0; u2 < 8; ++u2) x[u2] = p[(size_t)u2 * DIM];
    if (SUM) {
#pragma unroll
      for (int u2 = 0; u2 < 8; ++u2) s += x[u2];
    }
    union { unsigned int u4[4]; s16x8 v; } seg;
#pragma unroll
    for (int u2 = 0; u2 < 4; ++u2) seg.u4[u2] = cvtpk(x[2 * u2], x[2 * u2 + 1]);
    *(s16x8*)&dst[d * 136 + j8 * 8] = seg.v;
  }
  return s;
}

// ---------------- Pass A: S^T[e][d] = sum_j v[j][e] k[j][d] via MFMA; store bf16 ----------------
__global__ __launch_bounds__(256) void pass_a(const float* __restrict__ k0,
                                              const float* __restrict__ k1,
                                              const float* __restrict__ v,
                                              float* __restrict__ ws) {
  __shared__ __align__(16) unsigned short skT[64 * 136];   // kT[d][j]
  __shared__ __align__(16) unsigned short svT[64 * 136];   // vT[e][j]
  __shared__ float spart[4][64];                           // fp32 ksum partials
  int bid = blockIdx.x;
  int m = bid >> 9, rem = bid & 511, hh = rem >> 5, c = rem & 31;
  const float* kp = (m ? k1 : k0) + (size_t)hh * SEQ * DIM + (size_t)c * CHUNK * DIM;
  const float* vp = v + (size_t)hh * SEQ * DIM + (size_t)c * CHUNK * DIM;
  int t = threadIdx.x;

  float s = gather_T<true, 256>(kp, skT, t);
  gather_T<false, 256>(vp, svT, t);
  spart[t >> 6][t & 63] = s;
  __syncthreads();

  // ksum[d] in full fp32 (pre-rounding values)
  if (t < 64)
    ws[KS_OFF + (size_t)bid * 64 + t] = spart[0][t] + spart[1][t] + spart[2][t] + spart[3][t];

  // MFMA: wave w -> e-tile w; A = vT (m=e), B = kT rows (k=j, n=d)
  int w = t >> 6, L = t & 63, g = L >> 4, cL = L & 15;
  f32x4 acc[4];
#pragma unroll
  for (int ct = 0; ct < 4; ++ct) acc[ct] = (f32x4){0.f, 0.f, 0.f, 0.f};
#pragma unroll
  for (int ks = 0; ks < 4; ++ks) {
    s16x8 aF = *(const s16x8*)&svT[(w * 16 + cL) * 136 + ks * 32 + g * 8];
#pragma unroll
    for (int ct = 0; ct < 4; ++ct) {
      s16x8 bF = *(const s16x8*)&skT[(ct * 16 + cL) * 136 + ks * 32 + g * 8];
      acc[ct] = __builtin_amdgcn_mfma_f32_16x16x32_bf16(aF, bF, acc[ct], 0, 0, 0);
    }
  }
  // C/D layout: col = cL (=d-local), row = g*4+r (=e-local); store bf16
  unsigned short* Sp = (unsigned short*)ws + (size_t)bid * 4096;
#pragma unroll
  for (int ct = 0; ct < 4; ++ct)
#pragma unroll
    for (int r = 0; r < 4; ++r)
      Sp[(size_t)(w * 16 + g * 4 + r) * 64 + ct * 16 + cL] = f2bf(acc[ct][r]);
}

// ---------------- Pass B: exclusive prefix over chunks; all 32 loads in flight ----------------
__global__ __launch_bounds__(256) void pass_b(float* __restrict__ ws) {
  int t = threadIdx.x;
  if (blockIdx.x < 256) {
    int gid = blockIdx.x * 256 + t;            // [0, 65536)
    int mh = gid >> 11, de2 = gid & 2047;      // mh in [0,32)
    unsigned int* p = (unsigned int*)ws + (size_t)mh * NC * 2048 + de2;
    unsigned int x[NC];
#pragma unroll
    for (int c = 0; c < NC; ++c) x[c] = p[(size_t)c * 2048];
    float r0 = 0.f, r1 = 0.f;
#pragma unroll
    for (int c = 0; c < NC; ++c) {
      unsigned int xc = x[c];
      p[(size_t)c * 2048] = (unsigned int)f2bf(r0) | ((unsigned int)f2bf(r1) << 16);
      r0 += bf2f_lo(xc & 0xFFFFu);
      r1 += __uint_as_float(xc & 0xFFFF0000u);
    }
  } else {
    int gid = (blockIdx.x - 256) * 256 + t;    // [0, 2048)
    int mh = gid >> 6, d = gid & 63;
    float* p = ws + KS_OFF + (size_t)mh * NC * 64 + d;
    float x[NC];
#pragma unroll
    for (int c = 0; c < NC; ++c) x[c] = p[(size_t)c * 64];
    float run = 0.f;
#pragma unroll
    for (int c = 0; c < NC; ++c) {
      p[(size_t)c * 64] = run;
      run += x[c];
    }
  }
}

// ---------------- Pass C: per-chunk output via MFMA, 8 waves, m-parallel ----------------
// Wave w owns (m=0, rt=w) and (m=1, rt=7-w): 18 QK + 20 PV + 16 inter MFMAs per wave (balanced).
// P^T computed via swapped-operand MFMA (i in lane dim); PV A-frag assembled in-register with
// cvt_pk + shfl (no P LDS buffer, no lgkm drains, no compute-section barriers).
__global__ __launch_bounds__(512, 4) void pass_c(const float* __restrict__ q0,
                                                 const float* __restrict__ q1,
                                                 const float* __restrict__ k0,
                                                 const float* __restrict__ k1,
                                                 const float* __restrict__ v,
                                                 const float* __restrict__ ws,
                                                 float* __restrict__ out) {
  __shared__ __align__(16) unsigned short svT[64 * 136];   // vT[e][j]  17408 B
  __shared__ __align__(16) union UBuf {
    struct {
      unsigned short sST[2][64 * 72];                      // S^T per m, 18432 B
      float skpref[2][64];                                 // 512 B
    } a;
    float exch[128 * 66];                                  // m1 accO exchange, 33792 B
  } u;
  __shared__ float sden[2][128];

  int hh = blockIdx.x >> 5, c = blockIdx.x & 31;
  int t = threadIdx.x;
  int w = t >> 6, L = t & 63, g = L >> 4, cL = L & 15;
  size_t off = (size_t)hh * SEQ * DIM + (size_t)c * CHUNK * DIM;
  const int rtS0 = w, rtS1 = 7 - w;

  gather_T<false, 512>(v + off, svT, t);

  // stage S^T (bf16) + ksum-prefix for both m: half-block each
  {
    int half = t >> 8, tt = t & 255;
    const unsigned short* Sp = (const unsigned short*)ws + (size_t)(half * 512 + hh * 32 + c) * 4096;
    const float* Kp = ws + KS_OFF + (size_t)(half * 512 + hh * 32 + c) * 64;
#pragma unroll
    for (int p2 = 0; p2 < 2; ++p2) {
      int idx = tt + p2 * 256;
      *(s16x8*)&u.a.sST[half][(idx >> 3) * 72 + (idx & 7) * 8] = *(const s16x8*)&Sp[idx * 8];
    }
    if (tt < 64) u.a.skpref[half][tt] = Kp[tt];
  }
  __syncthreads();

  f32x4 accO[2][4];
#pragma unroll
  for (int a = 0; a < 2; ++a)
#pragma unroll
    for (int b = 0; b < 4; ++b) accO[a][b] = (f32x4){0.f, 0.f, 0.f, 0.f};
  float dent[2] = {0.f, 0.f};
  s16x8 aq[2][2];

  // q loads + den(q . ksum_prefix) + inter O += q @ S_prefix
#pragma unroll
  for (int s2 = 0; s2 < 2; ++s2) {
    int rt = s2 ? rtS1 : rtS0;
    const float* qp = (s2 ? q1 : q0) + off;
    int row = rt * 16 + cL;
#pragma unroll
    for (int h = 0; h < 2; ++h) {
      const float* qb = qp + (size_t)row * DIM + h * 32 + g * 8;
      float4 a0 = *(const float4*)qb;
      float4 a1 = *(const float4*)(qb + 4);
      const float* kq = &u.a.skpref[s2][h * 32 + g * 8];
      dent[s2] += a0.x * kq[0] + a0.y * kq[1] + a0.z * kq[2] + a0.w * kq[3]
                + a1.x * kq[4] + a1.y * kq[5] + a1.z * kq[6] + a1.w * kq[7];
      aq[s2][h] = pack8(a0, a1);
    }
#pragma unroll
    for (int h = 0; h < 2; ++h)
#pragma unroll
      for (int et = 0; et < 4; ++et) {
        s16x8 bS = *(const s16x8*)&u.a.sST[s2][(et * 16 + cL) * 72 + h * 32 + g * 8];
        accO[s2][et] = __builtin_amdgcn_mfma_f32_16x16x32_bf16(aq[s2][h], bS, accO[s2][et], 0, 0, 0);
      }
  }

  // QK^T (swapped operands -> P^T: col=i=cL, row=j=g*4+r) + in-register transpose + PV
  {
    int srcA = cL + ((g & 1) << 5), srcB = srcA + 16;
    bool hiG = g >= 2;
#pragma unroll
    for (int s2 = 0; s2 < 2; ++s2) {
      int rt = s2 ? rtS1 : rtS0;
      const float* kp = (s2 ? k1 : k0) + off;
      for (int ks = 0; ks <= (rt >> 1); ++ks) {
        unsigned int E0e, E1e;
        {
          int jt = 2 * ks;
          const float* kb = kp + (size_t)(jt * 16 + cL) * DIM;
          float4 b0 = *(const float4*)(kb + g * 8);
          float4 b1 = *(const float4*)(kb + g * 8 + 4);
          float4 b2 = *(const float4*)(kb + 32 + g * 8);
          float4 b3 = *(const float4*)(kb + 32 + g * 8 + 4);
          s16x8 kf0 = pack8(b0, b1), kf1 = pack8(b2, b3);
          f32x4 C = (f32x4){0.f, 0.f, 0.f, 0.f};
          C = __builtin_amdgcn_mfma_f32_16x16x32_bf16(kf0, aq[s2][0], C, 0, 0, 0);
          C = __builtin_amdgcn_mfma_f32_16x16x32_bf16(kf1, aq[s2][1], C, 0, 0, 0);
          if (jt == rt) {                      // diagonal: zero j>i -> (g*4+r) > cL
#pragma unroll
            for (int r = 0; r < 4; ++r)
              if (g * 4 + r > cL) C[r] = 0.f;
          }
          dent[s2] += C[0] + C[1] + C[2] + C[3];
          E0e = cvtpk(C[0], C[1]); E1e = cvtpk(C[2], C[3]);
        }
        int S0o = 0, S1o = 0, S2o = 0, S3o = 0;
        if (2 * ks + 1 <= rt) {                // odd tile present (wave-uniform)
          int jt = 2 * ks + 1;
          const float* kb = kp + (size_t)(jt * 16 + cL) * DIM;
          float4 b0 = *(const float4*)(kb + g * 8);
          float4 b1 = *(const float4*)(kb + g * 8 + 4);
          float4 b2 = *(const float4*)(kb + 32 + g * 8);
          float4 b3 = *(const float4*)(kb + 32 + g * 8 + 4);
          s16x8 kf0 = pack8(b0, b1), kf1 = pack8(b2, b3);
          f32x4 C = (f32x4){0.f, 0.f, 0.f, 0.f};
          C = __builtin_amdgcn_mfma_f32_16x16x32_bf16(kf0, aq[s2][0], C, 0, 0, 0);
          C = __builtin_amdgcn_mfma_f32_16x16x32_bf16(kf1, aq[s2][1], C, 0, 0, 0);
          if (jt == rt) {
#pragma unroll
            for (int r = 0; r < 4; ++r)
              if (g * 4 + r > cL) C[r] = 0.f;
          }
          dent[s2] += C[0] + C[1] + C[2] + C[3];
          unsigned int E0o = cvtpk(C[0], C[1]), E1o = cvtpk(C[2], C[3]);
          S0o = __shfl((int)E0o, srcA); S1o = __shfl((int)E1o, srcA);
          S2o = __shfl((int)E0o, srcB); S3o = __shfl((int)E1o, srcB);
        }
        int S0e = __shfl((int)E0e, srcA); int S1e = __shfl((int)E1e, srcA);
        int S2e = __shfl((int)E0e, srcB); int S3e = __shfl((int)E1e, srcB);
        union { int d4[4]; s16x8 v8; } ap;
        ap.d4[0] = hiG ? S0o : S0e;
        ap.d4[1] = hiG ? S1o : S1e;
        ap.d4[2] = hiG ? S2o : S2e;
        ap.d4[3] = hiG ? S3o : S3e;
#pragma unroll
        for (int et = 0; et < 4; ++et) {
          s16x8 bV = *(const s16x8*)&svT[(et * 16 + cL) * 136 + ks * 32 + g * 8];
          accO[s2][et] = __builtin_amdgcn_mfma_f32_16x16x32_bf16(ap.v8, bV, accO[s2][et], 0, 0, 0);
        }
      }
    }
  }

  // den: reduce over g (full j and d coverage for row i=cL), publish per row/m
#pragma unroll
  for (int s2 = 0; s2 < 2; ++s2) {
    float dt = dent[s2];
    dt += __shfl_xor(dt, 16);
    dt += __shfl_xor(dt, 32);
    dent[s2] = dt;
  }
  if (L < 16) {
    sden[0][rtS0 * 16 + L] = dent[0];
    sden[1][rtS1 * 16 + L] = dent[1];
  }
  __syncthreads();   // compute done: sST/skpref dead, union free; sden visible

  // publish m1 accO into exchange (stride 66: 2-way bank alias = free)
#pragma unroll
  for (int et = 0; et < 4; ++et)
#pragma unroll
    for (int r = 0; r < 4; ++r)
      u.exch[(rtS1 * 16 + g * 4 + r) * 66 + et * 16 + cL] = accO[1][et][r];
  __syncthreads();

  // finalize rows rt0*16..+16: O = m0 + m1, scale by 1/(den0+den1+eps)
  float* op = out + off;
#pragma unroll
  for (int r = 0; r < 4; ++r) {
    int row = rtS0 * 16 + g * 4 + r;
    float inv = 1.f / (sden[0][row] + sden[1][row] + EPSV);
#pragma unroll
    for (int et = 0; et < 4; ++et) {
      float O = accO[0][et][r] + u.exch[row * 66 + et * 16 + cL];
      op[(size_t)row * DIM + et * 16 + cL] = O * inv;
    }
  }
}

extern "C" void kernel_launch(void* const* d_in, const int* in_sizes, int n_in,
                              void* d_out, int out_size, void* d_ws, size_t ws_size,
                              hipStream_t stream) {
  const float* q  = (const float*)d_in[0];
  const float* k  = (const float*)d_in[1];
  const float* qr = (const float*)d_in[2];
  const float* kr = (const float*)d_in[3];
  const float* v  = (const float*)d_in[4];
  float* out = (float*)d_out;
  float* ws  = (float*)d_ws;

  hipLaunchKernelGGL(pass_a, dim3(1024), dim3(256), 0, stream, k, kr, v, ws);
  hipLaunchKernelGGL(pass_b, dim3(264), dim3(256), 0, stream, ws);
  hipLaunchKernelGGL(pass_c, dim3(512), dim3(512), 0, stream, q, qr, k, kr, v, ws, out);
}